// Round 15
// baseline (131.530 us; speedup 1.0000x reference)
//
#include <hip/hip_runtime.h>
#include <math.h>

#define NQ 12
#define DEPTH 3
#define FEAT 768
#define NCLS 10
#define NW 8                 // waves per block
#define AMPS 8               // complex amps per thread
#define PI_HALF 1.57079632679489662f

typedef float v2f __attribute__((ext_vector_type(2)));

// ---------- packed complex helpers (VOP3P packed fp32) ----------
__device__ __forceinline__ v2f pk_mul_bl(v2f A, v2f z) {
    v2f d;
    asm("v_pk_mul_f32 %0, %1, %2 op_sel:[0,0] op_sel_hi:[1,0]"
        : "=v"(d) : "v"(A), "v"(z));
    return d;
}
__device__ __forceinline__ void pk_fma_bl(v2f& d, v2f A, v2f z) {
    asm("v_pk_fma_f32 %0, %1, %2, %0 op_sel:[0,0,0] op_sel_hi:[1,0,1]"
        : "+v"(d) : "v"(A), "v"(z));
}
__device__ __forceinline__ void pk_fma_bh(v2f& d, v2f B, v2f z) {
    asm("v_pk_fma_f32 %0, %1, %2, %0 op_sel:[0,1,0] op_sel_hi:[1,1,1]"
        : "+v"(d) : "v"(B), "v"(z));
}
// z' = S*z + P*p (complex): As={sr,si} Bs={-si,sr} Ap={pr,pi} Bp={-pi,pr}
__device__ __forceinline__ v2f cgate(v2f As, v2f Bs, v2f Ap, v2f Bp, v2f z, v2f p) {
    v2f d = pk_mul_bl(As, z);
    pk_fma_bh(d, Bs, z);
    pk_fma_bl(d, Ap, p);
    pk_fma_bh(d, Bp, p);
    return d;
}

// ---------- lane-swap helpers ----------
#define DPPF(v, ctrl) __int_as_float(__builtin_amdgcn_update_dpp(0, __float_as_int(v), (ctrl), 0xF, 0xF, true))

// DPP-based (VALU pipe) — used in allred where latency matters
template<int M>
__device__ __forceinline__ float swx(float v) {
    if constexpr (M == 1) {
        return DPPF(v, 0xB1);
    } else if constexpr (M == 2) {
        return DPPF(v, 0x4E);
    } else if constexpr (M == 4) {
        float t = DPPF(v, 0x141);
        return DPPF(t, 0x1B);
    } else if constexpr (M == 8) {
        return DPPF(v, 0x128);
    } else if constexpr (M == 16) {
        return __int_as_float(__builtin_amdgcn_ds_swizzle(__float_as_int(v), 0x401F));
    } else {
        return __shfl_xor(v, 32, 64);
    }
}

// DS-swizzle-based (DS pipe) — used in gate partner fetch to offload the VALU.
// bitmode offset = (xor<<10) | 0x1F.  Valid for M in {1,2,4,8,16}.
template<int M>
__device__ __forceinline__ v2f swxd2(v2f z) {
    if constexpr (M == 32) {
        v2f p;
        p.x = __shfl_xor(z.x, 32, 64);
        p.y = __shfl_xor(z.y, 32, 64);
        return p;
    } else {
        const int off = (M << 10) | 0x1F;
        v2f p;
        p.x = __int_as_float(__builtin_amdgcn_ds_swizzle(__float_as_int(z.x), off));
        p.y = __int_as_float(__builtin_amdgcn_ds_swizzle(__float_as_int(z.y), off));
        return p;
    }
}

__device__ __forceinline__ float allred(float v) {
    v += swx<1>(v); v += swx<2>(v); v += swx<4>(v);
    v += swx<8>(v); v += swx<16>(v); v += swx<32>(v);
    return v;
}

// ---------- state layouts ----------
// amp index i (bit11..bit0), wire q <-> bit (11-q).  Lane always: wire3=lane&32,
// wire4=lane&16, wire5=lane&8, wire6=lane&4, wire7=lane&2, wire8=lane&1.
// Layout A: wave=wires0-2 (lw bit2=w0,bit1=w1,bit0=w2); reg=wires9-11 (j&4=w9,j&2=w10,j&1=w11).
// Layout B: wave=wires9-11 (lw bit2=w9,...); reg=wires0-2 (j&4=w0, j&2=w1, j&1=w2).

template<int JM>
__device__ __forceinline__ void rot_reg(v2f (&z)[AMPS], const v2f* m) {
    const v2f A0 = m[0], B0 = m[1], P0 = m[2], Q0 = m[3];
    const v2f A1 = m[4], B1 = m[5], P1 = m[6], Q1 = m[7];
    #pragma unroll
    for (int j = 0; j < AMPS; ++j) if (!(j & JM)) {
        const int j1 = j | JM;
        v2f z0 = z[j], z1 = z[j1];
        z[j]  = cgate(A0, B0, P0, Q0, z0, z1);
        z[j1] = cgate(A1, B1, P1, Q1, z1, z0);
    }
}

template<int LM>
__device__ __forceinline__ void rot_lane(v2f (&z)[AMPS], const v2f* m, int lane) {
    // address-select the coefficient bank (b=0: m[0..3], b=1: m[4..7]) — no cndmask
    const v2f* mm = m + (((lane & LM) != 0) ? 4 : 0);
    const v2f As = mm[0], Bs = mm[1], Ap = mm[2], Bp = mm[3];
    #pragma unroll
    for (int j = 0; j < AMPS; ++j) {
        v2f p = swxd2<LM>(z[j]);      // partner fetch on DS pipe
        z[j] = cgate(As, Bs, Ap, Bp, z[j], p);
    }
}

// transpose wave-field <-> reg-field (A<->B), 1 exchange pass
__device__ __forceinline__ void relayout(v2f (&z)[AMPS], v2f (*ex)[AMPS][64], int lw, int lane) {
    #pragma unroll
    for (int k = 0; k < AMPS; ++k) ex[lw][k][lane] = z[k];
    __syncthreads();
    #pragma unroll
    for (int k = 0; k < AMPS; ++k) z[k] = ex[k][lw][lane];
    __syncthreads();
}

template<int JC, int JT>
__device__ __forceinline__ void cnot_rr(v2f (&z)[AMPS]) {
    #pragma unroll
    for (int j = 0; j < AMPS; ++j) if ((j & JC) && !(j & JT)) {
        const int j1 = j | JT;
        v2f t = z[j]; z[j] = z[j1]; z[j1] = t;
    }
}

// Block = 1 sample, 8 waves x 64 lanes x 8 amps = 4096 amps.
// Alternating A/B layouts (1 relayout/layer); ENTIRE ring-CNOT block fused
// into the layer's LDS exchange read addresses (CNOTs are GF(2) index
// permutations); layer-2 ring Heisenberg-absorbed into observables.
__global__ __launch_bounds__(512) void qcircuit_fz2(
    const float* __restrict__ x,    // [B, 768]
    const float* __restrict__ Wp,   // [12, 768]
    const float* __restrict__ w,    // [3, 12, 3]
    const float* __restrict__ Wo,   // [10, 12]
    const float* __restrict__ bo,   // [10]
    float* __restrict__ out)        // [B, 10]
{
    const int t = threadIdx.x;
    const int wave = t >> 6;
    const int lane = t & 63;
    const int b = blockIdx.x;

    __shared__ v2f mcoef[DEPTH * NQ][8];   // packed gate coefficients
    __shared__ v2f ex[NW][AMPS][64];       // 32 KB exchange buffer
    __shared__ float red[NW][NQ];
    __shared__ float sh_dot[NQ];
    __shared__ float sh_ac[NQ], sh_as[NQ], zsh[NQ];

    if (t < DEPTH * NQ) {
        float phi = w[t * 3 + 0], th = w[t * 3 + 1], om = w[t * 3 + 2];
        float ct = cosf(0.5f * th), sn = sinf(0.5f * th);
        float a0 = -0.5f * (phi + om);
        float a1 = 0.5f * (phi - om);
        float c0 = cosf(a0), s0 = sinf(a0);
        float c1 = cosf(a1), s1 = sinf(a1);
        float m00r = c0 * ct,  m00i = s0 * ct;
        float m01r = -c1 * sn, m01i = -s1 * sn;
        float m10r = c1 * sn,  m10i = -s1 * sn;
        float m11r = c0 * ct,  m11i = -s0 * ct;
        mcoef[t][0] = v2f{m00r, m00i};  mcoef[t][1] = v2f{-m00i, m00r};
        mcoef[t][2] = v2f{m01r, m01i};  mcoef[t][3] = v2f{-m01i, m01r};
        mcoef[t][4] = v2f{m11r, m11i};  mcoef[t][5] = v2f{-m11i, m11r};
        mcoef[t][6] = v2f{m10r, m10i};  mcoef[t][7] = v2f{-m10i, m10r};
    }

    // ---------------- projection: wave v owns q=v (waves 0-3 also q=v+8) ----
    {
        const float4* x4  = reinterpret_cast<const float4*>(x + (size_t)b * FEAT);
        const float4* Wp4 = reinterpret_cast<const float4*>(Wp);
        float4 xv[3];
        #pragma unroll
        for (int c = 0; c < 3; ++c) xv[c] = x4[lane + 64 * c];
        float accA = 0.f;
        #pragma unroll
        for (int c = 0; c < 3; ++c) {
            float4 wv = Wp4[wave * 192 + lane + 64 * c];
            accA += xv[c].x * wv.x + xv[c].y * wv.y + xv[c].z * wv.z + xv[c].w * wv.w;
        }
        accA = allred(accA);
        float accB = 0.f;
        if (wave < 4) {
            #pragma unroll
            for (int c = 0; c < 3; ++c) {
                float4 wv = Wp4[(wave + 8) * 192 + lane + 64 * c];
                accB += xv[c].x * wv.x + xv[c].y * wv.y + xv[c].z * wv.z + xv[c].w * wv.w;
            }
            accB = allred(accB);
        }
        if (lane == 0) {
            sh_dot[wave] = accA;
            if (wave < 4) sh_dot[wave + 8] = accB;
        }
    }
    __syncthreads();
    if (t < NQ) {
        float h = 0.5f * (tanhf(sh_dot[t]) * PI_HALF);
        sh_ac[t] = cosf(h);
        sh_as[t] = sinf(h);
    }
    __syncthreads();

    // ---------------- direct product-state init (layout A) ----------------
    int lw = wave;
    float pr[AMPS];
    float L0 = ((wave & 4) ? sh_as[0] : sh_ac[0]);
    L0 *= (wave & 2) ? sh_as[1] : sh_ac[1];
    L0 *= (wave & 1) ? sh_as[2] : sh_ac[2];
    L0 *= (lane & 32) ? sh_as[3] : sh_ac[3];
    L0 *= (lane & 16) ? sh_as[4] : sh_ac[4];
    L0 *= (lane &  8) ? sh_as[5] : sh_ac[5];
    L0 *= (lane &  4) ? sh_as[6] : sh_ac[6];
    L0 *= (lane &  2) ? sh_as[7] : sh_ac[7];
    L0 *= (lane &  1) ? sh_as[8] : sh_ac[8];
    pr[0] = L0;
    #pragma unroll
    for (int wbit = 0; wbit < 3; ++wbit) {       // wire = 11-wbit (A: w9=j&4,w10=j&2,w11=j&1)
        const int bmask = 1 << wbit;
        const float cw = sh_ac[11 - wbit], sw = sh_as[11 - wbit];
        #pragma unroll
        for (int j = 0; j < AMPS; ++j) {
            if (j < bmask) {
                pr[j | bmask] = pr[j] * sw;
                pr[j] = pr[j] * cw;
            }
        }
    }
    v2f z[AMPS];
    #pragma unroll
    for (int j = 0; j < AMPS; ++j) z[j] = v2f{pr[j], 0.f};

    // ================ layer 0 (start in A) ================
    {
        const v2f* mb = &mcoef[0 * NQ][0];
        rot_reg < 4>(z, mb + 9 * 8);                // w9  (reg in A)
        rot_reg < 2>(z, mb + 10 * 8);               // w10
        rot_reg < 1>(z, mb + 11 * 8);               // w11
        rot_lane<32>(z, mb + 3 * 8, lane);          // w3
        rot_lane<16>(z, mb + 4 * 8, lane);          // w4
        rot_lane< 8>(z, mb + 5 * 8, lane);          // w5
        rot_lane< 4>(z, mb + 6 * 8, lane);          // w6
        rot_lane< 2>(z, mb + 7 * 8, lane);          // w7
        rot_lane< 1>(z, mb + 8 * 8, lane);          // w8
        relayout(z, ex, lw, lane);                  // A -> B
        rot_reg < 4>(z, mb + 0 * 8);                // w0  (reg in B)
        rot_reg < 2>(z, mb + 1 * 8);                // w1
        rot_reg < 1>(z, mb + 2 * 8);                // w2
        // ---- ring r=1 in B, fused ----
        cnot_rr< 4,  2>(z);              // (0,1)  (register renames)
        cnot_rr< 2,  1>(z);              // (1,2)
        // (2,3),(3,4),(4,5),(5,6),(6,7),(7,8),(8,9),(11,0) fused into one LDS
        // pass; (9,10),(10,11) are lw relabels.
        {
            const int woff = (lane & 1) << 2;        // (8,9): ctrl w8=lane&1, tgt w9=lw&4
            int Ls = lane;
            Ls ^= (Ls & 2) >> 1;                     // (7,8)
            Ls ^= (Ls & 4) >> 1;                     // (6,7)
            Ls ^= (Ls & 8) >> 1;                     // (5,6)
            Ls ^= (Ls & 16) >> 1;                    // (4,5)
            Ls ^= (Ls & 32) >> 1;                    // (3,4)
            int lw2 = lw ^ ((lw & 4) ? 2 : 0);       // (9,10) relabel
            lw2 ^= (lw2 & 2) ? 1 : 0;                // (10,11) relabel
            const int wlc = (lw2 & 1) << 2;          // (11,0): ctrl w11=lw2&1, tgt w0=j&4
            #pragma unroll
            for (int k = 0; k < AMPS; ++k) ex[lw][k][lane] = z[k];
            __syncthreads();
            #pragma unroll
            for (int k = 0; k < AMPS; ++k)
                z[k] = ex[lw ^ woff][k ^ wlc][Ls ^ ((k & 1) << 5)];  // (2,3): k&1 -> ^32
            __syncthreads();
            lw = lw2;
        }
    }
    // ================ layer 1 (in B) ================
    {
        const v2f* mb = &mcoef[1 * NQ][0];
        rot_reg < 4>(z, mb + 0 * 8);                // w0 (reg in B)
        rot_reg < 2>(z, mb + 1 * 8);                // w1
        rot_reg < 1>(z, mb + 2 * 8);                // w2
        rot_lane<32>(z, mb + 3 * 8, lane);
        rot_lane<16>(z, mb + 4 * 8, lane);
        rot_lane< 8>(z, mb + 5 * 8, lane);
        rot_lane< 4>(z, mb + 6 * 8, lane);
        rot_lane< 2>(z, mb + 7 * 8, lane);
        rot_lane< 1>(z, mb + 8 * 8, lane);
        relayout(z, ex, lw, lane);                  // B -> A
        rot_reg < 4>(z, mb + 9 * 8);                // w9 (reg in A)
        rot_reg < 2>(z, mb + 10 * 8);               // w10
        rot_reg < 1>(z, mb + 11 * 8);               // w11
        // ---- ring r=2 in A, fully fused into one LDS pass ----
        {
            lw ^= (lw & 4) >> 2;                     // (0,2) relabel
            int Ls = lane;
            Ls ^= (Ls & 4) >> 2;                     // (6,8)
            Ls ^= (Ls & 8) >> 2;                     // (5,7)
            Ls ^= (Ls & 16) >> 2;                    // (4,6)
            Ls ^= (Ls & 32) >> 2;                    // (3,5)
            const int klx = ((lane & 2) << 1) ^ ((lane & 1) << 1);  // (7,9),(8,10)
            #pragma unroll
            for (int k = 0; k < AMPS; ++k) ex[lw][k][lane] = z[k];
            __syncthreads();
            #pragma unroll
            for (int k = 0; k < AMPS; ++k) {
                const int LW = lw ^ ((k & 1) << 1) ^ ((k & 2) << 1);   // (11,1),(10,0)
                const int K  = k ^ ((k & 4) >> 2) ^ klx;               // (9,11),(8,10),(7,9)
                const int Lr = Ls ^ ((LW & 1) << 4) ^ ((LW & 2) << 4); // (2,4),(1,3)
                z[k] = ex[LW][K][Lr];
            }
            __syncthreads();
        }
    }
    // ================ layer 2 (in A) ================
    {
        const v2f* mb = &mcoef[2 * NQ][0];
        rot_reg < 4>(z, mb + 9 * 8);                // w9 (reg in A)
        rot_reg < 2>(z, mb + 10 * 8);               // w10
        rot_reg < 1>(z, mb + 11 * 8);               // w11
        rot_lane<32>(z, mb + 3 * 8, lane);
        rot_lane<16>(z, mb + 4 * 8, lane);
        rot_lane< 8>(z, mb + 5 * 8, lane);
        rot_lane< 4>(z, mb + 6 * 8, lane);
        rot_lane< 2>(z, mb + 7 * 8, lane);
        rot_lane< 1>(z, mb + 8 * 8, lane);
        relayout(z, ex, lw, lane);                  // A -> B
        rot_reg < 4>(z, mb + 0 * 8);                // w0 (reg in B)
        rot_reg < 2>(z, mb + 1 * 8);                // w1
        rot_reg < 1>(z, mb + 2 * 8);                // w2
        // ring r=3 absorbed into observables (Heisenberg).
    }

    // ---------------- PauliZ expectations (layout B; conjugated masks) ------
    // B: w0=j&4 w1=j&2 w2=j&1; w3..w8 = lane bits; w9=lw&4 w10=lw&2 w11=lw&1.
    // O0={3,6,9} O1={4,7,10} O2={5,8,11} O3={0,3} O4={1,4} O5={2,5}
    // O6={0,3,6} O7={1,4,7} O8={2,5,8} O9={0,3,6,9} O10={1,4,7,10} O11={2,5,8,11}
    float ptot = 0.f, zn4 = 0.f, zn2 = 0.f, zn1 = 0.f;
    #pragma unroll
    for (int j = 0; j < AMPS; ++j) {
        float p = z[j].x * z[j].x + z[j].y * z[j].y;
        ptot += p;
        if (j & 4) zn4 += p;
        if (j & 2) zn2 += p;
        if (j & 1) zn1 += p;
    }
    const float S4 = ptot - 2.f * zn4;   // w0 sign (j&4)
    const float S2 = ptot - 2.f * zn2;   // w1 sign (j&2)
    const float S1 = ptot - 2.f * zn1;   // w2 sign (j&1)
    const bool p36 = ((lane >> 5) ^ (lane >> 2)) & 1;   // parity {w3,w6}
    const bool p18 = ((lane >> 4) ^ (lane >> 1)) & 1;   // parity {w4,w7}
    const bool p9  = ((lane >> 3) ^ lane) & 1;          // parity {w5,w8}

    const float a0 = allred(p36 ? -ptot : ptot);        // O0 base
    const float a1 = allred(p18 ? -ptot : ptot);        // O1 base
    const float a2 = allred(p9  ? -ptot : ptot);        // O2 base
    const float a3 = allred((lane & 32) ? -S4 : S4);    // O3
    const float a4 = allred((lane & 16) ? -S2 : S2);    // O4
    const float a5 = allred((lane &  8) ? -S1 : S1);    // O5
    const float a6 = allred(p36 ? -S4 : S4);            // O6 / O9 base
    const float a7 = allred(p18 ? -S2 : S2);            // O7 / O10 base
    const float a8 = allred(p9  ? -S1 : S1);            // O8 / O11 base

    const float W9  = (lw & 4) ? -1.f : 1.f;
    const float W10 = (lw & 2) ? -1.f : 1.f;
    const float W11 = (lw & 1) ? -1.f : 1.f;
    float zp[NQ];
    zp[0]  = W9 * a0;   zp[1]  = W10 * a1;  zp[2]  = W11 * a2;
    zp[3]  = a3;        zp[4]  = a4;        zp[5]  = a5;
    zp[6]  = a6;        zp[7]  = a7;        zp[8]  = a8;
    zp[9]  = W9 * a6;   zp[10] = W10 * a7;  zp[11] = W11 * a8;

    if (lane == 0) {
        #pragma unroll
        for (int q = 0; q < NQ; ++q) red[wave][q] = zp[q];
    }
    __syncthreads();
    if (t < NQ) {
        float s = 0.f;
        #pragma unroll
        for (int v = 0; v < NW; ++v) s += red[v][t];
        zsh[t] = s;
    }
    __syncthreads();

    // ---------------- output head ----------------
    if (t < NCLS) {
        float o = bo[t];
        #pragma unroll
        for (int q = 0; q < NQ; ++q) o = fmaf(zsh[q], Wo[t * NQ + q], o);
        out[(size_t)b * NCLS + t] = o;
    }
}

extern "C" void kernel_launch(void* const* d_in, const int* in_sizes, int n_in,
                              void* d_out, int out_size, void* d_ws, size_t ws_size,
                              hipStream_t stream) {
    const float* x  = (const float*)d_in[0];   // [B,768]
    const float* Wp = (const float*)d_in[1];   // [12,768]
    const float* w  = (const float*)d_in[2];   // [3,12,3]
    const float* Wo = (const float*)d_in[3];   // [10,12]
    const float* bo = (const float*)d_in[4];   // [10]
    float* out = (float*)d_out;

    const int B = in_sizes[0] / FEAT;          // 4096
    qcircuit_fz2<<<B, 512, 0, stream>>>(x, Wp, w, Wo, bo, out);
}

// Round 16
// 126.029 us; speedup vs baseline: 1.0436x; 1.0436x over previous
//
#include <hip/hip_runtime.h>
#include <math.h>

#define NQ 12
#define DEPTH 3
#define FEAT 768
#define NCLS 10
#define NW 8                 // waves per block
#define AMPS 8               // complex amps per thread
#define PI_HALF 1.57079632679489662f

typedef float v2f __attribute__((ext_vector_type(2)));

// ---------- packed complex helpers (VOP3P packed fp32) ----------
__device__ __forceinline__ v2f pk_mul_bl(v2f A, v2f z) {
    v2f d;
    asm("v_pk_mul_f32 %0, %1, %2 op_sel:[0,0] op_sel_hi:[1,0]"
        : "=v"(d) : "v"(A), "v"(z));
    return d;
}
__device__ __forceinline__ void pk_fma_bl(v2f& d, v2f A, v2f z) {
    asm("v_pk_fma_f32 %0, %1, %2, %0 op_sel:[0,0,0] op_sel_hi:[1,0,1]"
        : "+v"(d) : "v"(A), "v"(z));
}
__device__ __forceinline__ void pk_fma_bh(v2f& d, v2f B, v2f z) {
    asm("v_pk_fma_f32 %0, %1, %2, %0 op_sel:[0,1,0] op_sel_hi:[1,1,1]"
        : "+v"(d) : "v"(B), "v"(z));
}
// z' = S*z + P*p (complex): As={sr,si} Bs={-si,sr} Ap={pr,pi} Bp={-pi,pr}
__device__ __forceinline__ v2f cgate(v2f As, v2f Bs, v2f Ap, v2f Bp, v2f z, v2f p) {
    v2f d = pk_mul_bl(As, z);
    pk_fma_bh(d, Bs, z);
    pk_fma_bl(d, Ap, p);
    pk_fma_bh(d, Bp, p);
    return d;
}

// ---------- lane-swap helpers (DPP, low latency) ----------
#define DPPF(v, ctrl) __int_as_float(__builtin_amdgcn_update_dpp(0, __float_as_int(v), (ctrl), 0xF, 0xF, true))

template<int M>
__device__ __forceinline__ float swx(float v) {
    if constexpr (M == 1) {
        return DPPF(v, 0xB1);
    } else if constexpr (M == 2) {
        return DPPF(v, 0x4E);
    } else if constexpr (M == 4) {
        float t = DPPF(v, 0x141);
        return DPPF(t, 0x1B);
    } else if constexpr (M == 8) {
        return DPPF(v, 0x128);
    } else if constexpr (M == 16) {
        return __int_as_float(__builtin_amdgcn_ds_swizzle(__float_as_int(v), 0x401F));
    } else {
        return __shfl_xor(v, 32, 64);
    }
}

template<int M>
__device__ __forceinline__ v2f swx2(v2f z) {
    v2f p;
    p.x = swx<M>(z.x);
    p.y = swx<M>(z.y);
    return p;
}

__device__ __forceinline__ float allred(float v) {
    v += swx<1>(v); v += swx<2>(v); v += swx<4>(v);
    v += swx<8>(v); v += swx<16>(v); v += swx<32>(v);
    return v;
}

// ---------- state layouts ----------
// amp index i (bit11..bit0), wire q <-> bit (11-q).  Lane always: wire3=lane&32,
// wire4=lane&16, wire5=lane&8, wire6=lane&4, wire7=lane&2, wire8=lane&1.
// Layout A: wave=wires0-2 (lw bit2=w0,bit1=w1,bit0=w2); reg=wires9-11 (j&4=w9,j&2=w10,j&1=w11).
// Layout B: wave=wires9-11 (lw bit2=w9,...); reg=wires0-2 (j&4=w0, j&2=w1, j&1=w2).

template<int JM>
__device__ __forceinline__ void rot_reg(v2f (&z)[AMPS], const v2f* m) {
    const v2f A0 = m[0], B0 = m[1], P0 = m[2], Q0 = m[3];
    const v2f A1 = m[4], B1 = m[5], P1 = m[6], Q1 = m[7];
    #pragma unroll
    for (int j = 0; j < AMPS; ++j) if (!(j & JM)) {
        const int j1 = j | JM;
        v2f z0 = z[j], z1 = z[j1];
        z[j]  = cgate(A0, B0, P0, Q0, z0, z1);
        z[j1] = cgate(A1, B1, P1, Q1, z1, z0);
    }
}

template<int LM>
__device__ __forceinline__ void rot_lane(v2f (&z)[AMPS], const v2f* m, int lane) {
    // address-select the coefficient bank (b=0: m[0..3], b=1: m[4..7]) — no cndmask
    const v2f* mm = m + (((lane & LM) != 0) ? 4 : 0);
    const v2f As = mm[0], Bs = mm[1], Ap = mm[2], Bp = mm[3];
    #pragma unroll
    for (int j = 0; j < AMPS; ++j) {
        v2f p = swx2<LM>(z[j]);       // DPP partner fetch (low latency)
        z[j] = cgate(As, Bs, Ap, Bp, z[j], p);
    }
}

// transpose wave-field <-> reg-field (A<->B), 1 exchange pass
__device__ __forceinline__ void relayout(v2f (&z)[AMPS], v2f (*ex)[AMPS][64], int lw, int lane) {
    #pragma unroll
    for (int k = 0; k < AMPS; ++k) ex[lw][k][lane] = z[k];
    __syncthreads();
    #pragma unroll
    for (int k = 0; k < AMPS; ++k) z[k] = ex[k][lw][lane];
    __syncthreads();
}

template<int JC, int JT>
__device__ __forceinline__ void cnot_rr(v2f (&z)[AMPS]) {
    #pragma unroll
    for (int j = 0; j < AMPS; ++j) if ((j & JC) && !(j & JT)) {
        const int j1 = j | JT;
        v2f t = z[j]; z[j] = z[j1]; z[j1] = t;
    }
}

// Block = 1 sample, 8 waves x 64 lanes x 8 amps = 4096 amps.
// Alternating A/B layouts (1 relayout/layer); ENTIRE ring-CNOT block fused
// into the layer's LDS exchange read addresses (CNOTs are GF(2) index
// permutations); layer-2 ring Heisenberg-absorbed into observables.
__global__ __launch_bounds__(512) void qcircuit_fz3(
    const float* __restrict__ x,    // [B, 768]
    const float* __restrict__ Wp,   // [12, 768]
    const float* __restrict__ w,    // [3, 12, 3]
    const float* __restrict__ Wo,   // [10, 12]
    const float* __restrict__ bo,   // [10]
    float* __restrict__ out)        // [B, 10]
{
    const int t = threadIdx.x;
    const int wave = t >> 6;
    const int lane = t & 63;
    const int b = blockIdx.x;

    __shared__ v2f mcoef[DEPTH * NQ][8];   // packed gate coefficients
    __shared__ v2f ex[NW][AMPS][64];       // 32 KB exchange buffer
    __shared__ float red[NW][NQ];
    __shared__ float sh_dot[NQ];
    __shared__ float sh_ac[NQ], sh_as[NQ], zsh[NQ];

    if (t < DEPTH * NQ) {
        float phi = w[t * 3 + 0], th = w[t * 3 + 1], om = w[t * 3 + 2];
        float ct = cosf(0.5f * th), sn = sinf(0.5f * th);
        float a0 = -0.5f * (phi + om);
        float a1 = 0.5f * (phi - om);
        float c0 = cosf(a0), s0 = sinf(a0);
        float c1 = cosf(a1), s1 = sinf(a1);
        float m00r = c0 * ct,  m00i = s0 * ct;
        float m01r = -c1 * sn, m01i = -s1 * sn;
        float m10r = c1 * sn,  m10i = -s1 * sn;
        float m11r = c0 * ct,  m11i = -s0 * ct;
        mcoef[t][0] = v2f{m00r, m00i};  mcoef[t][1] = v2f{-m00i, m00r};
        mcoef[t][2] = v2f{m01r, m01i};  mcoef[t][3] = v2f{-m01i, m01r};
        mcoef[t][4] = v2f{m11r, m11i};  mcoef[t][5] = v2f{-m11i, m11r};
        mcoef[t][6] = v2f{m10r, m10i};  mcoef[t][7] = v2f{-m10i, m10r};
    }

    // ---------------- projection: wave v owns q=v (waves 0-3 also q=v+8) ----
    {
        const float4* x4  = reinterpret_cast<const float4*>(x + (size_t)b * FEAT);
        const float4* Wp4 = reinterpret_cast<const float4*>(Wp);
        float4 xv[3];
        #pragma unroll
        for (int c = 0; c < 3; ++c) xv[c] = x4[lane + 64 * c];
        float accA = 0.f;
        #pragma unroll
        for (int c = 0; c < 3; ++c) {
            float4 wv = Wp4[wave * 192 + lane + 64 * c];
            accA += xv[c].x * wv.x + xv[c].y * wv.y + xv[c].z * wv.z + xv[c].w * wv.w;
        }
        accA = allred(accA);
        float accB = 0.f;
        if (wave < 4) {
            #pragma unroll
            for (int c = 0; c < 3; ++c) {
                float4 wv = Wp4[(wave + 8) * 192 + lane + 64 * c];
                accB += xv[c].x * wv.x + xv[c].y * wv.y + xv[c].z * wv.z + xv[c].w * wv.w;
            }
            accB = allred(accB);
        }
        if (lane == 0) {
            sh_dot[wave] = accA;
            if (wave < 4) sh_dot[wave + 8] = accB;
        }
    }
    __syncthreads();
    if (t < NQ) {
        float h = 0.5f * (tanhf(sh_dot[t]) * PI_HALF);
        sh_ac[t] = cosf(h);
        sh_as[t] = sinf(h);
    }
    __syncthreads();

    // ---------------- direct product-state init (layout A) ----------------
    int lw = wave;
    float pr[AMPS];
    float L0 = ((wave & 4) ? sh_as[0] : sh_ac[0]);
    L0 *= (wave & 2) ? sh_as[1] : sh_ac[1];
    L0 *= (wave & 1) ? sh_as[2] : sh_ac[2];
    L0 *= (lane & 32) ? sh_as[3] : sh_ac[3];
    L0 *= (lane & 16) ? sh_as[4] : sh_ac[4];
    L0 *= (lane &  8) ? sh_as[5] : sh_ac[5];
    L0 *= (lane &  4) ? sh_as[6] : sh_ac[6];
    L0 *= (lane &  2) ? sh_as[7] : sh_ac[7];
    L0 *= (lane &  1) ? sh_as[8] : sh_ac[8];
    pr[0] = L0;
    #pragma unroll
    for (int wbit = 0; wbit < 3; ++wbit) {       // wire = 11-wbit (A: w9=j&4,w10=j&2,w11=j&1)
        const int bmask = 1 << wbit;
        const float cw = sh_ac[11 - wbit], sw = sh_as[11 - wbit];
        #pragma unroll
        for (int j = 0; j < AMPS; ++j) {
            if (j < bmask) {
                pr[j | bmask] = pr[j] * sw;
                pr[j] = pr[j] * cw;
            }
        }
    }
    v2f z[AMPS];
    #pragma unroll
    for (int j = 0; j < AMPS; ++j) z[j] = v2f{pr[j], 0.f};

    // ================ layer 0 (start in A) ================
    {
        const v2f* mb = &mcoef[0 * NQ][0];
        rot_reg < 4>(z, mb + 9 * 8);                // w9  (reg in A)
        rot_reg < 2>(z, mb + 10 * 8);               // w10
        rot_reg < 1>(z, mb + 11 * 8);               // w11
        rot_lane<32>(z, mb + 3 * 8, lane);          // w3
        rot_lane<16>(z, mb + 4 * 8, lane);          // w4
        rot_lane< 8>(z, mb + 5 * 8, lane);          // w5
        rot_lane< 4>(z, mb + 6 * 8, lane);          // w6
        rot_lane< 2>(z, mb + 7 * 8, lane);          // w7
        rot_lane< 1>(z, mb + 8 * 8, lane);          // w8
        relayout(z, ex, lw, lane);                  // A -> B
        rot_reg < 4>(z, mb + 0 * 8);                // w0  (reg in B)
        rot_reg < 2>(z, mb + 1 * 8);                // w1
        rot_reg < 1>(z, mb + 2 * 8);                // w2
        // ---- ring r=1 in B, fused ----
        cnot_rr< 4,  2>(z);              // (0,1)  (register renames)
        cnot_rr< 2,  1>(z);              // (1,2)
        // (2,3),(3,4),(4,5),(5,6),(6,7),(7,8),(8,9),(11,0) fused into one LDS
        // pass; (9,10),(10,11) are lw relabels.
        {
            const int woff = (lane & 1) << 2;        // (8,9): ctrl w8=lane&1, tgt w9=lw&4
            int Ls = lane;
            Ls ^= (Ls & 2) >> 1;                     // (7,8)
            Ls ^= (Ls & 4) >> 1;                     // (6,7)
            Ls ^= (Ls & 8) >> 1;                     // (5,6)
            Ls ^= (Ls & 16) >> 1;                    // (4,5)
            Ls ^= (Ls & 32) >> 1;                    // (3,4)
            int lw2 = lw ^ ((lw & 4) ? 2 : 0);       // (9,10) relabel
            lw2 ^= (lw2 & 2) ? 1 : 0;                // (10,11) relabel
            const int wlc = (lw2 & 1) << 2;          // (11,0): ctrl w11=lw2&1, tgt w0=j&4
            #pragma unroll
            for (int k = 0; k < AMPS; ++k) ex[lw][k][lane] = z[k];
            __syncthreads();
            #pragma unroll
            for (int k = 0; k < AMPS; ++k)
                z[k] = ex[lw ^ woff][k ^ wlc][Ls ^ ((k & 1) << 5)];  // (2,3): k&1 -> ^32
            __syncthreads();
            lw = lw2;
        }
    }
    // ================ layer 1 (in B) ================
    {
        const v2f* mb = &mcoef[1 * NQ][0];
        rot_reg < 4>(z, mb + 0 * 8);                // w0 (reg in B)
        rot_reg < 2>(z, mb + 1 * 8);                // w1
        rot_reg < 1>(z, mb + 2 * 8);                // w2
        rot_lane<32>(z, mb + 3 * 8, lane);
        rot_lane<16>(z, mb + 4 * 8, lane);
        rot_lane< 8>(z, mb + 5 * 8, lane);
        rot_lane< 4>(z, mb + 6 * 8, lane);
        rot_lane< 2>(z, mb + 7 * 8, lane);
        rot_lane< 1>(z, mb + 8 * 8, lane);
        relayout(z, ex, lw, lane);                  // B -> A
        rot_reg < 4>(z, mb + 9 * 8);                // w9 (reg in A)
        rot_reg < 2>(z, mb + 10 * 8);               // w10
        rot_reg < 1>(z, mb + 11 * 8);               // w11
        // ---- ring r=2 in A, fully fused into one LDS pass ----
        {
            lw ^= (lw & 4) >> 2;                     // (0,2) relabel
            int Ls = lane;
            Ls ^= (Ls & 4) >> 2;                     // (6,8)
            Ls ^= (Ls & 8) >> 2;                     // (5,7)
            Ls ^= (Ls & 16) >> 2;                    // (4,6)
            Ls ^= (Ls & 32) >> 2;                    // (3,5)
            const int klx = ((lane & 2) << 1) ^ ((lane & 1) << 1);  // (7,9),(8,10)
            #pragma unroll
            for (int k = 0; k < AMPS; ++k) ex[lw][k][lane] = z[k];
            __syncthreads();
            #pragma unroll
            for (int k = 0; k < AMPS; ++k) {
                const int LW = lw ^ ((k & 1) << 1) ^ ((k & 2) << 1);   // (11,1),(10,0)
                const int K  = k ^ ((k & 4) >> 2) ^ klx;               // (9,11),(8,10),(7,9)
                const int Lr = Ls ^ ((LW & 1) << 4) ^ ((LW & 2) << 4); // (2,4),(1,3)
                z[k] = ex[LW][K][Lr];
            }
            __syncthreads();
        }
    }
    // ================ layer 2 (in A) ================
    {
        const v2f* mb = &mcoef[2 * NQ][0];
        rot_reg < 4>(z, mb + 9 * 8);                // w9 (reg in A)
        rot_reg < 2>(z, mb + 10 * 8);               // w10
        rot_reg < 1>(z, mb + 11 * 8);               // w11
        rot_lane<32>(z, mb + 3 * 8, lane);
        rot_lane<16>(z, mb + 4 * 8, lane);
        rot_lane< 8>(z, mb + 5 * 8, lane);
        rot_lane< 4>(z, mb + 6 * 8, lane);
        rot_lane< 2>(z, mb + 7 * 8, lane);
        rot_lane< 1>(z, mb + 8 * 8, lane);
        relayout(z, ex, lw, lane);                  // A -> B
        rot_reg < 4>(z, mb + 0 * 8);                // w0 (reg in B)
        rot_reg < 2>(z, mb + 1 * 8);                // w1
        rot_reg < 1>(z, mb + 2 * 8);                // w2
        // ring r=3 absorbed into observables (Heisenberg).
    }

    // ---------------- PauliZ expectations (layout B; conjugated masks) ------
    // B: w0=j&4 w1=j&2 w2=j&1; w3..w8 = lane bits; w9=lw&4 w10=lw&2 w11=lw&1.
    // O0={3,6,9} O1={4,7,10} O2={5,8,11} O3={0,3} O4={1,4} O5={2,5}
    // O6={0,3,6} O7={1,4,7} O8={2,5,8} O9={0,3,6,9} O10={1,4,7,10} O11={2,5,8,11}
    float ptot = 0.f, zn4 = 0.f, zn2 = 0.f, zn1 = 0.f;
    #pragma unroll
    for (int j = 0; j < AMPS; ++j) {
        float p = z[j].x * z[j].x + z[j].y * z[j].y;
        ptot += p;
        if (j & 4) zn4 += p;
        if (j & 2) zn2 += p;
        if (j & 1) zn1 += p;
    }
    const float S4 = ptot - 2.f * zn4;   // w0 sign (j&4)
    const float S2 = ptot - 2.f * zn2;   // w1 sign (j&2)
    const float S1 = ptot - 2.f * zn1;   // w2 sign (j&1)
    const bool p36 = ((lane >> 5) ^ (lane >> 2)) & 1;   // parity {w3,w6}
    const bool p18 = ((lane >> 4) ^ (lane >> 1)) & 1;   // parity {w4,w7}
    const bool p9  = ((lane >> 3) ^ lane) & 1;          // parity {w5,w8}

    const float a0 = allred(p36 ? -ptot : ptot);        // O0 base
    const float a1 = allred(p18 ? -ptot : ptot);        // O1 base
    const float a2 = allred(p9  ? -ptot : ptot);        // O2 base
    const float a3 = allred((lane & 32) ? -S4 : S4);    // O3
    const float a4 = allred((lane & 16) ? -S2 : S2);    // O4
    const float a5 = allred((lane &  8) ? -S1 : S1);    // O5
    const float a6 = allred(p36 ? -S4 : S4);            // O6 / O9 base
    const float a7 = allred(p18 ? -S2 : S2);            // O7 / O10 base
    const float a8 = allred(p9  ? -S1 : S1);            // O8 / O11 base

    const float W9  = (lw & 4) ? -1.f : 1.f;
    const float W10 = (lw & 2) ? -1.f : 1.f;
    const float W11 = (lw & 1) ? -1.f : 1.f;
    float zp[NQ];
    zp[0]  = W9 * a0;   zp[1]  = W10 * a1;  zp[2]  = W11 * a2;
    zp[3]  = a3;        zp[4]  = a4;        zp[5]  = a5;
    zp[6]  = a6;        zp[7]  = a7;        zp[8]  = a8;
    zp[9]  = W9 * a6;   zp[10] = W10 * a7;  zp[11] = W11 * a8;

    if (lane == 0) {
        #pragma unroll
        for (int q = 0; q < NQ; ++q) red[wave][q] = zp[q];
    }
    __syncthreads();
    if (t < NQ) {
        float s = 0.f;
        #pragma unroll
        for (int v = 0; v < NW; ++v) s += red[v][t];
        zsh[t] = s;
    }
    __syncthreads();

    // ---------------- output head ----------------
    if (t < NCLS) {
        float o = bo[t];
        #pragma unroll
        for (int q = 0; q < NQ; ++q) o = fmaf(zsh[q], Wo[t * NQ + q], o);
        out[(size_t)b * NCLS + t] = o;
    }
}

extern "C" void kernel_launch(void* const* d_in, const int* in_sizes, int n_in,
                              void* d_out, int out_size, void* d_ws, size_t ws_size,
                              hipStream_t stream) {
    const float* x  = (const float*)d_in[0];   // [B,768]
    const float* Wp = (const float*)d_in[1];   // [12,768]
    const float* w  = (const float*)d_in[2];   // [3,12,3]
    const float* Wo = (const float*)d_in[3];   // [10,12]
    const float* bo = (const float*)d_in[4];   // [10]
    float* out = (float*)d_out;

    const int B = in_sizes[0] / FEAT;          // 4096
    qcircuit_fz3<<<B, 512, 0, stream>>>(x, Wp, w, Wo, bo, out);
}